// Round 1
// baseline (297.351 us; speedup 1.0000x reference)
//
#include <hip/hip_runtime.h>

// Reference collapses: softmax over a size-1 axis => weights == 1 => attn == v.
// out = chem_16 @ (Wo @ Wv)^T + (Wo @ bv + bo).  fp_16 / Wq / Wk are dead code.
// DIM=16, N_HEADS=4 (irrelevant after collapse), B=2097152.

#define DIM 16
#define BATCH 2097152

// Kernel A: fold weights. ws[0..255] = Wc[j][i] = sum_k Wo[j][k] * Wv[k][i]
//           ws[256..271] = bc[j] = bo[j] + sum_k Wo[j][k] * bv[k]
__global__ void fold_weights_kernel(const float* __restrict__ in_proj_weight,
                                    const float* __restrict__ in_proj_bias,
                                    const float* __restrict__ out_proj_weight,
                                    const float* __restrict__ out_proj_bias,
                                    float* __restrict__ ws) {
    int t = threadIdx.x;            // 256 threads
    int j = t >> 4;
    int i = t & 15;
    // Wv row k is in_proj_weight row (32 + k)
    float acc = 0.0f;
#pragma unroll
    for (int k = 0; k < 16; ++k)
        acc += out_proj_weight[j * 16 + k] * in_proj_weight[(32 + k) * 16 + i];
    ws[t] = acc;
    if (t < 16) {
        float b = out_proj_bias[t];
#pragma unroll
        for (int k = 0; k < 16; ++k)
            b += out_proj_weight[t * 16 + k] * in_proj_bias[32 + k];
        ws[256 + t] = b;
    }
}

// Kernel B: out[row] = x[row] @ Wc^T + bc.  One row per thread.
// Wc/bc accessed with compile-time-constant indices off a kernel arg pointer
// => uniform addresses => s_load into SGPRs, FMAs are v_fmac_f32 v,s,v.
__global__ __launch_bounds__(256) void affine_rows_kernel(
    const float* __restrict__ x,
    const float* __restrict__ wfold,   // 256 weights + 16 bias
    float* __restrict__ out) {
    size_t row = (size_t)blockIdx.x * 256 + threadIdx.x;
    if (row >= (size_t)BATCH) return;

    const float4* xv = (const float4*)(x + row * DIM);
    float4 x0 = xv[0];
    float4 x1 = xv[1];
    float4 x2 = xv[2];
    float4 x3 = xv[3];
    float xr[16] = {x0.x, x0.y, x0.z, x0.w,
                    x1.x, x1.y, x1.z, x1.w,
                    x2.x, x2.y, x2.z, x2.w,
                    x3.x, x3.y, x3.z, x3.w};

    float acc[16];
#pragma unroll
    for (int j = 0; j < 16; ++j)
        acc[j] = wfold[256 + j];
#pragma unroll
    for (int j = 0; j < 16; ++j) {
#pragma unroll
        for (int i = 0; i < 16; ++i)
            acc[j] += xr[i] * wfold[j * 16 + i];
    }

    float4* ov = (float4*)(out + row * DIM);
    ov[0] = make_float4(acc[0],  acc[1],  acc[2],  acc[3]);
    ov[1] = make_float4(acc[4],  acc[5],  acc[6],  acc[7]);
    ov[2] = make_float4(acc[8],  acc[9],  acc[10], acc[11]);
    ov[3] = make_float4(acc[12], acc[13], acc[14], acc[15]);
}

extern "C" void kernel_launch(void* const* d_in, const int* in_sizes, int n_in,
                              void* d_out, int out_size, void* d_ws, size_t ws_size,
                              hipStream_t stream) {
    // setup_inputs order: fp_16, chem_16, in_proj_weight, in_proj_bias,
    //                     out_proj_weight, out_proj_bias
    const float* chem        = (const float*)d_in[1];
    const float* in_proj_w   = (const float*)d_in[2];
    const float* in_proj_b   = (const float*)d_in[3];
    const float* out_proj_w  = (const float*)d_in[4];
    const float* out_proj_b  = (const float*)d_in[5];
    float* out = (float*)d_out;
    float* ws  = (float*)d_ws;   // needs 272 floats = 1088 bytes

    fold_weights_kernel<<<1, 256, 0, stream>>>(in_proj_w, in_proj_b,
                                               out_proj_w, out_proj_b, ws);

    int blocks = BATCH / 256;    // 2097152 / 256 = 8192, exact
    affine_rows_kernel<<<blocks, 256, 0, stream>>>(chem, ws, out);
}

// Round 2
// 285.907 us; speedup vs baseline: 1.0400x; 1.0400x over previous
//
#include <hip/hip_runtime.h>

// Reference collapses: softmax over a size-1 axis => weights == 1 => attn == v.
// out = chem_16 @ (Wo @ Wv)^T + (Wo @ bv + bo).  fp_16 / Wq / Wk are dead code.
// DIM=16, B=2097152.
//
// R1: coalesced layout. 4 consecutive lanes co-own one row (one float4 quarter
// each); quarters exchanged via __shfl_xor (quad-perm, stays in-wave). Each
// lane computes its 4 output columns with a per-lane pre-permuted 4x4x4 weight
// block in VGPRs (loaded once, L1-served). All global loads/stores are
// lane-contiguous float4 => 16 cache lines per instruction instead of 64.

#define DIM 16
#define BATCH 2097152

// Kernel A: fold weights into d_ws.
//   ws[0..255]   = Wc[j][i] = sum_k Wo[j][k] * Wv[k][i]
//   ws[256..271] = bc[j]    = bo[j] + sum_k Wo[j][k] * bv[k]
__global__ void fold_weights_kernel(const float* __restrict__ in_proj_weight,
                                    const float* __restrict__ in_proj_bias,
                                    const float* __restrict__ out_proj_weight,
                                    const float* __restrict__ out_proj_bias,
                                    float* __restrict__ ws) {
    int t = threadIdx.x;            // 256 threads
    int j = t >> 4;
    int i = t & 15;
    float acc = 0.0f;
#pragma unroll
    for (int k = 0; k < 16; ++k)
        acc += out_proj_weight[j * 16 + k] * in_proj_weight[(32 + k) * 16 + i];
    ws[t] = acc;
    if (t < 16) {
        float b = out_proj_bias[t];
#pragma unroll
        for (int k = 0; k < 16; ++k)
            b += out_proj_weight[t * 16 + k] * in_proj_bias[32 + k];
        ws[256 + t] = b;
    }
}

__device__ __forceinline__ float4 shfl_xor_f4(float4 v, int mask) {
    float4 r;
    r.x = __shfl_xor(v.x, mask, 64);
    r.y = __shfl_xor(v.y, mask, 64);
    r.z = __shfl_xor(v.z, mask, 64);
    r.w = __shfl_xor(v.w, mask, 64);
    return r;
}

// Kernel B: lane t handles quarter q = t&3 of rows (blockIdx*256 + t/4 + 64k),
// k = 0..3. Global float4 index = blockIdx*1024 + 256k + t  (coalesced).
__global__ __launch_bounds__(256) void affine_rows_coalesced(
    const float* __restrict__ x,
    const float* __restrict__ wfold,   // 256 weights + 16 bias
    float* __restrict__ out) {
    const int t = threadIdx.x;
    const int q = t & 3;

    // Per-lane permuted weights: w[m][jp].{x,y,z,w} = Wc[(q*4+jp)*16 + (q^m)*4 + j]
    // Addresses depend only on q => 4 distinct cache lines per load instr, L1-hit.
    float4 w[4][4];
#pragma unroll
    for (int m = 0; m < 4; ++m) {
        const int qc = q ^ m;
#pragma unroll
        for (int jp = 0; jp < 4; ++jp)
            w[m][jp] = *(const float4*)(wfold + (q * 4 + jp) * 16 + qc * 4);
    }
    const float4 bias = *(const float4*)(wfold + 256 + q * 4);

    const float4* xv = (const float4*)x;
    float4* ov = (float4*)out;
    const size_t base = (size_t)blockIdx.x * 1024;

#pragma unroll
    for (int k = 0; k < 4; ++k) {
        const size_t idx = base + (size_t)k * 256 + t;
        float4 xs0 = xv[idx];              // own quarter q
        float4 xs1 = shfl_xor_f4(xs0, 1);  // quarter q^1
        float4 xs2 = shfl_xor_f4(xs0, 2);  // quarter q^2
        float4 xs3 = shfl_xor_f4(xs0, 3);  // quarter q^3

        float4 acc = bias;
#define ACCUM(m, xsv)                                                   \
        acc.x += xsv.x * w[m][0].x + xsv.y * w[m][0].y +                \
                 xsv.z * w[m][0].z + xsv.w * w[m][0].w;                 \
        acc.y += xsv.x * w[m][1].x + xsv.y * w[m][1].y +                \
                 xsv.z * w[m][1].z + xsv.w * w[m][1].w;                 \
        acc.z += xsv.x * w[m][2].x + xsv.y * w[m][2].y +                \
                 xsv.z * w[m][2].z + xsv.w * w[m][2].w;                 \
        acc.w += xsv.x * w[m][3].x + xsv.y * w[m][3].y +                \
                 xsv.z * w[m][3].z + xsv.w * w[m][3].w;
        ACCUM(0, xs0)
        ACCUM(1, xs1)
        ACCUM(2, xs2)
        ACCUM(3, xs3)
#undef ACCUM

        ov[idx] = acc;                     // coalesced store, quarter q of row
    }
}

extern "C" void kernel_launch(void* const* d_in, const int* in_sizes, int n_in,
                              void* d_out, int out_size, void* d_ws, size_t ws_size,
                              hipStream_t stream) {
    // setup_inputs order: fp_16, chem_16, in_proj_weight, in_proj_bias,
    //                     out_proj_weight, out_proj_bias
    const float* chem        = (const float*)d_in[1];
    const float* in_proj_w   = (const float*)d_in[2];
    const float* in_proj_b   = (const float*)d_in[3];
    const float* out_proj_w  = (const float*)d_in[4];
    const float* out_proj_b  = (const float*)d_in[5];
    float* out = (float*)d_out;
    float* ws  = (float*)d_ws;   // needs 272 floats = 1088 bytes

    fold_weights_kernel<<<1, 256, 0, stream>>>(in_proj_w, in_proj_b,
                                               out_proj_w, out_proj_b, ws);

    const int blocks = BATCH / 256;   // 8192, exact
    affine_rows_coalesced<<<blocks, 256, 0, stream>>>(chem, ws, out);
}